// Round 26
// baseline (1109.236 us; speedup 1.0000x reference)
//
#include <hip/hip_runtime.h>
#include <hip/hip_bf16.h>

#define SEQ 2048
#define DMODEL 768
#define NHEAD 8
#define DQK 128
#define DV 192
#define QKVN 1344
#define FFI 1536
#define NP 256
#define DP 128
#define DPI 256
#define NPR 65536
#define KVB 64
#define NSPLIT 2

#define EPS_RMS 1.1920929e-07f
#define EPS_LN 1e-5f
#define LOG2E 1.4426950408889634f
#define C1_LOG2E 0.5770780163555852f   // 0.4 * log2(e)
#define C2_LOG2E -14.426950408889634f  // -10 * log2(e)

typedef __attribute__((ext_vector_type(8))) short bf16x8;
typedef __attribute__((ext_vector_type(4))) short bf16x4;
typedef __attribute__((ext_vector_type(4))) float f32x4;

__device__ inline float wave_sum(float v) {
#pragma unroll
  for (int o = 32; o > 0; o >>= 1) v += __shfl_xor(v, o, 64);
  return v;
}
__device__ inline unsigned short f2bf(float x) {
  unsigned int u = __float_as_uint(x);
  u += 0x7fffu + ((u >> 16) & 1u);
  return (unsigned short)(u >> 16);
}
__device__ inline float bf2f(unsigned short x) {
  unsigned int u = ((unsigned int)x) << 16;
  return __uint_as_float(u);
}

__global__ void pos_kernel(float* __restrict__ pos) {
  int i = blockIdx.x, l = threadIdx.x;
  float f = (l == 0) ? 0.1f * (float)i : 0.0f;
  pos[i * 128 + l] = f;
  pos[i * 128 + 64 + l] = f;
}

__global__ void rowscale_kernel(const float* __restrict__ x, float* __restrict__ sc, int cols) {
  size_t row = blockIdx.x;
  int l = threadIdx.x;
  const float* xr = x + row * cols;
  float ss = 0.f;
  for (int c = l; c < cols; c += 64) { float v = xr[c]; ss += v * v; }
  ss = wave_sum(ss);
  if (l == 0) sc[row] = rsqrtf(ss / (float)cols + EPS_RMS);
}

// y = rmsnorm(x,w) + res; also writes sc[row] = inv-rms of y
__global__ void rmsres_kernel(const float* __restrict__ x, const float* __restrict__ w,
                              const float* res, float* y, int cols, float* __restrict__ sc) {
  size_t row = blockIdx.x;
  int l = threadIdx.x;
  const float* xr = x + row * cols;
  float ss = 0.f;
  for (int c = l; c < cols; c += 64) { float v = xr[c]; ss += v * v; }
  ss = wave_sum(ss);
  float r = rsqrtf(ss / (float)cols + EPS_RMS);
  float* yr = y + row * cols;
  const float* rr = res + row * cols;
  float ss2 = 0.f;
  for (int c = l; c < cols; c += 64) {
    float v = xr[c] * r * w[c] + rr[c];
    yr[c] = v;
    ss2 += v * v;
  }
  ss2 = wave_sum(ss2);
  if (l == 0) sc[row] = rsqrtf(ss2 / (float)cols + EPS_RMS);
}

// ===== batched weight transpose+convert: all 24 weights in one launch =====
struct ConvBatch {
  const float* src[24];
  unsigned short* dst[24];
  int K[24];
  int N[24];
  int base[24];
};

__global__ __launch_bounds__(256) void convT_batch(ConvBatch cb, int nw) {
  __shared__ float ls[32][33];
  int bid = blockIdx.x;
  int w = 0;
  while (w + 1 < nw && bid >= cb.base[w + 1]) w++;
  int local = bid - cb.base[w];
  int K = cb.K[w], N = cb.N[w];
  int ntn = N >> 5;
  int n0 = (local % ntn) * 32, k0 = (local / ntn) * 32;
  const float* W = cb.src[w];
  unsigned short* Wt = cb.dst[w];
  int t = threadIdx.x;
  int c = t & 31, r4 = t >> 5;
#pragma unroll
  for (int p = 0; p < 4; p++) {
    int r = r4 + p * 8;
    ls[r][c] = W[(size_t)(k0 + r) * N + n0 + c];
  }
  __syncthreads();
#pragma unroll
  for (int p = 0; p < 4; p++) {
    int n = r4 + p * 8, k = t & 31;
    Wt[(size_t)(n0 + n) * K + k0 + k] = f2bf(ls[k][n]);
  }
}

// build pairwise combined bias: [j][384] = [0 x256 | pw_v_b[j]]
__global__ void biasbuild_kernel(const float* __restrict__ pw_v_b, float* __restrict__ b384) {
  int j = blockIdx.x, t = threadIdx.x;
  b384[j * 384 + t] = (t < 256) ? 0.f : pw_v_b[j * DP + t - 256];
}

// ===== templated MFMA GEMM: 64x128 or 64x64 tile, reg-prefetch, XCD swizzle =====
// AMODE: 0 = f32 A (+opt rmsnorm scale), 1 = bf16 A, 2 = combine(2 Opart splits, lbuf),
//        3 = bf16 A (+rmsnorm scale). CBF: C bf16. RBF: resid is bf16. BN64: 64-wide N tile.
template<int AMODE, int CBF, int RBF = 0, int BN64 = 0>
__global__ __launch_bounds__(256) void gemm_k(const void* __restrict__ Av,
    const unsigned short* __restrict__ Bt, void* __restrict__ Cv,
    int M, int N, int K, int nbx,
    const float* __restrict__ bias, const void* __restrict__ resid, int act,
    const float* __restrict__ ascale, const float* __restrict__ aw,
    const float* __restrict__ lb = nullptr) {
  constexpr int BN = BN64 ? 64 : 128;
  constexpr int NC = BN64 ? 2 : 4;
  __shared__ unsigned short As[64 * 32];
  __shared__ unsigned short Bs[BN * 32];
  int t = threadIdx.x;
  int nwg = gridDim.x, bid = blockIdx.x;
  int qq = nwg >> 3, rr = nwg & 7, xc = bid & 7, ii = bid >> 3;
  int swz = (xc < rr ? xc * (qq + 1) : rr * (qq + 1) + (xc - rr) * qq) + ii;
  int bm = (swz / nbx) * 64, bn = (swz % nbx) * BN;
  int w = t >> 6, l = t & 63;
  int wr = (w >> 1) * 32, wc = (w & 1) * (BN / 2);
  int lo = l & 15, hi = l >> 4;
  f32x4 acc[2][NC];
#pragma unroll
  for (int q = 0; q < 2; q++)
#pragma unroll
    for (int cb = 0; cb < NC; cb++) acc[q][cb] = (f32x4){0.f, 0.f, 0.f, 0.f};

  int arow = t >> 2, acs = (t & 3) * 8;
  int brow = BN64 ? (t >> 2) : (t >> 1);
  int bks  = BN64 ? ((t & 3) * 8) : ((t & 1) * 16);
  int bok = (bn + brow < N);
  const unsigned short* bsrc = Bt + (size_t)(bok ? bn + brow : 0) * K + bks;

  float4 pa0, pa1;
  bf16x8 pab, pc1, pb0, pb1;
  float linv = 1.f;
  const bf16x8 zb = {0, 0, 0, 0, 0, 0, 0, 0};

  {
    if (AMODE == 2) {
      const unsigned short* Op = (const unsigned short*)Av;
      size_t base = (size_t)(bm + arow) * K + acs;
      pab = *(const bf16x8*)(Op + base);
      pc1 = *(const bf16x8*)(Op + (size_t)SEQ * K + base);
      int h = acs / DV;
      linv = 1.0f / (lb[(size_t)h * SEQ + bm + arow] +
                     lb[(size_t)(NHEAD + h) * SEQ + bm + arow]);
    } else if (AMODE == 1 || AMODE == 3) {
      pab = *(const bf16x8*)((const unsigned short*)Av + (size_t)(bm + arow) * K + acs);
    } else {
      const float* A = (const float*)Av;
      pa0 = *(const float4*)(A + (size_t)(bm + arow) * K + acs);
      pa1 = *(const float4*)(A + (size_t)(bm + arow) * K + acs + 4);
    }
    pb0 = bok ? *(const bf16x8*)(bsrc) : zb;
    if (!BN64) pb1 = bok ? *(const bf16x8*)(bsrc + 8) : zb;
  }

  for (int k0 = 0; k0 < K; k0 += 32) {
    if (k0) __syncthreads();
    {
      int byte = (arow * 64 + acs * 2) ^ ((arow & 7) << 4);
      if (AMODE == 2) {
        bf16x8 cmb;
#pragma unroll
        for (int e = 0; e < 8; e++)
          cmb[e] = (short)f2bf((bf2f((unsigned short)pab[e]) +
                                bf2f((unsigned short)pc1[e])) * linv);
        *(bf16x8*)((char*)As + byte) = cmb;
      } else if (AMODE == 3) {
        float s = ascale[bm + arow];
        bf16x8 sc8;
#pragma unroll
        for (int e = 0; e < 8; e++)
          sc8[e] = (short)f2bf(bf2f((unsigned short)pab[e]) * s * aw[k0 + acs + e]);
        *(bf16x8*)((char*)As + byte) = sc8;
      } else if (AMODE == 1) {
        *(bf16x8*)((char*)As + byte) = pab;
      } else {
        float4 v0 = pa0, v1 = pa1;
        if (ascale) {
          float s = ascale[bm + arow];
          v0.x *= s * aw[k0 + acs + 0]; v0.y *= s * aw[k0 + acs + 1];
          v0.z *= s * aw[k0 + acs + 2]; v0.w *= s * aw[k0 + acs + 3];
          v1.x *= s * aw[k0 + acs + 4]; v1.y *= s * aw[k0 + acs + 5];
          v1.z *= s * aw[k0 + acs + 6]; v1.w *= s * aw[k0 + acs + 7];
        }
        uint4 pk;
        pk.x = (unsigned int)f2bf(v0.x) | ((unsigned int)f2bf(v0.y) << 16);
        pk.y = (unsigned int)f2bf(v0.z) | ((unsigned int)f2bf(v0.w) << 16);
        pk.z = (unsigned int)f2bf(v1.x) | ((unsigned int)f2bf(v1.y) << 16);
        pk.w = (unsigned int)f2bf(v1.z) | ((unsigned int)f2bf(v1.w) << 16);
        *(uint4*)((char*)As + byte) = pk;
      }
      int b0 = (brow * 64 + bks * 2) ^ ((brow & 7) << 4);
      *(bf16x8*)((char*)Bs + b0) = pb0;
      if (!BN64) {
        int b1 = (brow * 64 + bks * 2 + 16) ^ ((brow & 7) << 4);
        *(bf16x8*)((char*)Bs + b1) = pb1;
      }
    }
    __syncthreads();
    if (k0 + 32 < K) {
      int kn = k0 + 32;
      if (AMODE == 2) {
        const unsigned short* Op = (const unsigned short*)Av;
        size_t base = (size_t)(bm + arow) * K + kn + acs;
        pab = *(const bf16x8*)(Op + base);
        pc1 = *(const bf16x8*)(Op + (size_t)SEQ * K + base);
        int h = (kn + acs) / DV;
        linv = 1.0f / (lb[(size_t)h * SEQ + bm + arow] +
                       lb[(size_t)(NHEAD + h) * SEQ + bm + arow]);
      } else if (AMODE == 1 || AMODE == 3) {
        pab = *(const bf16x8*)((const unsigned short*)Av + (size_t)(bm + arow) * K + kn + acs);
      } else {
        const float* A = (const float*)Av;
        pa0 = *(const float4*)(A + (size_t)(bm + arow) * K + kn + acs);
        pa1 = *(const float4*)(A + (size_t)(bm + arow) * K + kn + acs + 4);
      }
      pb0 = bok ? *(const bf16x8*)(bsrc + kn) : zb;
      if (!BN64) pb1 = bok ? *(const bf16x8*)(bsrc + kn + 8) : zb;
    }
    bf16x8 af[2], bfr[NC];
#pragma unroll
    for (int q = 0; q < 2; q++) {
      int r = wr + q * 16 + lo;
      af[q] = *(const bf16x8*)((char*)As + ((r * 64 + hi * 16) ^ ((r & 7) << 4)));
    }
#pragma unroll
    for (int cb = 0; cb < NC; cb++) {
      int n = wc + cb * 16 + lo;
      bfr[cb] = *(const bf16x8*)((char*)Bs + ((n * 64 + hi * 16) ^ ((n & 7) << 4)));
    }
#pragma unroll
    for (int q = 0; q < 2; q++)
#pragma unroll
      for (int cb = 0; cb < NC; cb++)
        acc[q][cb] = __builtin_amdgcn_mfma_f32_16x16x32_bf16(af[q], bfr[cb], acc[q][cb], 0, 0, 0);
  }
#pragma unroll
  for (int q = 0; q < 2; q++) {
#pragma unroll
    for (int cb = 0; cb < NC; cb++) {
      int gn = bn + wc + cb * 16 + lo;
      if (gn >= N) continue;
#pragma unroll
      for (int i = 0; i < 4; i++) {
        int gm = bm + wr + q * 16 + hi * 4 + i;
        float v = acc[q][cb][i];
        if (bias) v += bias[gn];
        if (act) v = fmaxf(v, 0.f);
        if (resid) {
          size_t ridx = (size_t)gm * N + gn;
          v += RBF ? bf2f(((const unsigned short*)resid)[ridx])
                   : ((const float*)resid)[ridx];
        }
        if (CBF) {
          ((unsigned short*)Cv)[(size_t)gm * N + gn] = f2bf(v);
        } else {
          ((float*)Cv)[(size_t)gm * N + gn] = v;
        }
      }
    }
  }
}

// merged q/k/v prep (bf16 input) -> bf16 outputs. grid (SEQ, 10)
__global__ void qkv_prep_kernel(const unsigned short* __restrict__ qkv,
                                const float* __restrict__ qw,
                                const float* __restrict__ kw, const float* __restrict__ vw,
                                const float* __restrict__ pos,
                                unsigned short* __restrict__ q_r, unsigned short* __restrict__ k_n,
                                unsigned short* __restrict__ v_t) {
  int i = blockIdx.x;
  int y = blockIdx.y;
  int l = threadIdx.x;
  if (y == 9) {
    const unsigned short* row = qkv + (size_t)i * QKVN + NHEAD * DQK + DQK;
    float x0 = bf2f(row[l]), x1 = bf2f(row[l + 64]), x2 = bf2f(row[l + 128]);
    float mu = wave_sum(x0 + x1 + x2) * (1.0f / 192.0f);
    float d0 = x0 - mu, d1 = x1 - mu, d2 = x2 - mu;
    float var = wave_sum(d0 * d0 + d1 * d1 + d2 * d2) * (1.0f / 192.0f);
    float rs = rsqrtf(var + EPS_LN);
    v_t[(size_t)l * SEQ + i] = f2bf(d0 * rs * vw[l]);
    v_t[(size_t)(l + 64) * SEQ + i] = f2bf(d1 * rs * vw[l + 64]);
    v_t[(size_t)(l + 128) * SEQ + i] = f2bf(d2 * rs * vw[l + 128]);
    return;
  }
  int off = (y < 8) ? y * DQK : NHEAD * DQK;
  const unsigned short* row = qkv + (size_t)i * QKVN + off;
  float a = bf2f(row[l]), b = bf2f(row[l + 64]);
  float mu = wave_sum(a + b) * (1.0f / 128.0f);
  float da = a - mu, db = b - mu;
  float var = wave_sum(da * da + db * db) * (1.0f / 128.0f);
  float rs = rsqrtf(var + EPS_LN);
  const float* w = (y < 8) ? qw : kw;
  float na = da * rs * w[l], nb = db * rs * w[l + 64];
  if (y < 8) { na *= 0.125f; nb *= 0.125f; }
  float p0 = pos[i * 128 + l], p1 = pos[i * 128 + 64 + l];
  float ra = na * cosf(p0) - nb * sinf(p0);
  float rb = nb * cosf(p1) + na * sinf(p1);
  if (y < 8) {
    unsigned short* o = q_r + ((size_t)y * SEQ + i) * DQK;
    o[l] = f2bf(ra); o[l + 64] = f2bf(rb);
  } else {
    unsigned short* o = k_n + (size_t)i * DQK;
    o[l] = f2bf(ra); o[l + 64] = f2bf(rb);
  }
}

// fused bias projection + scP writer
__global__ __launch_bounds__(256) void pb_kernel(const float* __restrict__ P,
    float* __restrict__ scP, const float* __restrict__ rmsw,
    const float* __restrict__ proj, float* __restrict__ pbt) {
  __shared__ float gs[32][130];
  __shared__ float projs[1024];
  int b = blockIdx.x, t = threadIdx.x;
  int row0 = b * 32;
  int wv = t >> 6, ln = t & 63;
  for (int f = t; f < 1024; f += 256) projs[f] = proj[f];
#pragma unroll
  for (int rr = 0; rr < 8; rr++) {
    int r = wv * 8 + rr;
    const float* src = P + (size_t)(row0 + r) * DP;
    float2 x = *(const float2*)(src + ln * 2);
    float ss = wave_sum(x.x * x.x + x.y * x.y);
    float rs = rsqrtf(ss * (1.0f / DP) + EPS_RMS);
    float g0 = x.x * rs * rmsw[ln * 2];
    float g1 = x.y * rs * rmsw[ln * 2 + 1];
    gs[r][ln * 2] = 0.5f * g0 * (1.0f + erff(g0 * 0.70710678118654752f));
    gs[r][ln * 2 + 1] = 0.5f * g1 * (1.0f + erff(g1 * 0.70710678118654752f));
    if (ln == 0) scP[row0 + r] = rs;
  }
  __syncthreads();
  int hh = t >> 5, r = t & 31;
  float acc = 0.f;
#pragma unroll 4
  for (int d = 0; d < 128; d++) acc += gs[r][d] * projs[d * 8 + hh];
  pbt[(size_t)hh * NPR + row0 + r] = acc;
}

// ===== split-K MFMA flash attention: fixed-max softmax (raw exp2/rcp), swapped QK,
//       l via MFMA ones-column, setprio around MFMA clusters.
//       grid (SEQ/64, NHEAD, NSPLIT). =====
__global__ __launch_bounds__(256) void attn_mfma(const unsigned short* __restrict__ q_r,
    const unsigned short* __restrict__ k_n, const unsigned short* __restrict__ v_t,
    const float* __restrict__ pbt, unsigned short* __restrict__ Opart,
    float* __restrict__ lbuf) {
  __shared__ unsigned short Ks[64 * 128];
  __shared__ unsigned short Vs[208 * 64];
  __shared__ unsigned short Ps[4][16 * 64];
  __shared__ float pb_lds[64];
  int ib = blockIdx.x, h = blockIdx.y, sp = blockIdx.z, t = threadIdx.x;
  int i0 = ib * 64;
  int w = t >> 6, l = t & 63;
  int lo = l & 15, hi = l >> 4;
  int kbeg = sp * (SEQ / NSPLIT), kend = kbeg + SEQ / NSPLIT;

  bf16x8 qf[4];
  {
    const unsigned short* qp = q_r + ((size_t)h * SEQ + i0 + w * 16 + lo) * DQK + hi * 8;
#pragma unroll
    for (int ks = 0; ks < 4; ks++) qf[ks] = *(const bf16x8*)(qp + ks * 32);
  }
  f32x4 o_acc[13];
#pragma unroll
  for (int vc = 0; vc < 13; vc++) o_acc[vc] = (f32x4){0.f, 0.f, 0.f, 0.f};

#pragma unroll
  for (int r4 = 0; r4 < 4; r4++) {
    int idx = t + 256 * r4;
    int row = 192 + (idx >> 6), key = idx & 63;
    int byte = (row * 128 + key * 2) ^ ((row & 7) << 4);
    *(unsigned short*)((char*)Vs + byte) = (row == 192) ? 0x3F80 : 0;
  }

  char* PsW = (char*)&Ps[w][0];
  int rg8 = (((w * 16 + lo) >> 3) << 3) + (hi >> 1);

  for (int k0 = kbeg; k0 < kend; k0 += KVB) {
    {
      int row = t >> 2, d0 = (t & 3) * 32;
      const unsigned short* src = k_n + (size_t)(k0 + row) * DQK + d0;
#pragma unroll
      for (int jj = 0; jj < 4; jj++) {
        bf16x8 a = *(const bf16x8*)(src + jj * 8);
        int byte = (row * 256 + (d0 + jj * 8) * 2) ^ ((row & 7) << 4);
        *(bf16x8*)((char*)Ks + byte) = a;
      }
    }
#pragma unroll
    for (int rep = 0; rep < 6; rep++) {
      int c = t + 256 * rep;
      int row = c >> 3, seg = c & 7;
      bf16x8 a = *(const bf16x8*)(v_t + (size_t)row * SEQ + k0 + seg * 8);
      int byte = (row * 128 + seg * 16) ^ ((row & 7) << 4);
      *(bf16x8*)((char*)Vs + byte) = a;
    }
    if (t < 64) {
      int rg = t >> 3, kg = t & 7;
      pb_lds[t] = C1_LOG2E * pbt[(size_t)h * NPR + ((i0 >> 3) + rg) * 256 + (k0 >> 3) + kg];
    }
    __syncthreads();
    f32x4 sacc[4];
#pragma unroll
    for (int kb = 0; kb < 4; kb++) sacc[kb] = (f32x4){0.f, 0.f, 0.f, 0.f};
    __builtin_amdgcn_s_setprio(1);
#pragma unroll
    for (int ks = 0; ks < 4; ks++) {
#pragma unroll
      for (int kb = 0; kb < 4; kb++) {
        int key = kb * 16 + lo;
        int byte = (key * 256 + (ks * 32 + hi * 8) * 2) ^ ((key & 7) << 4);
        bf16x8 kf = *(const bf16x8*)((char*)Ks + byte);
        sacc[kb] = __builtin_amdgcn_mfma_f32_16x16x32_bf16(kf, qf[ks], sacc[kb], 0, 0, 0);
      }
    }
    __builtin_amdgcn_s_setprio(0);
#pragma unroll
    for (int kb = 0; kb < 4; kb++) {
      float pb = pb_lds[rg8 + kb * 2];
      bf16x4 pk;
#pragma unroll
      for (int i = 0; i < 4; i++) {
        float x2 = fmaf(C1_LOG2E, sacc[kb][i], pb);
        float e = __builtin_amdgcn_exp2f(x2);
        float p = __builtin_amdgcn_exp2f(C2_LOG2E * __builtin_amdgcn_rcpf(e + 1.f));
        pk[i] = (short)f2bf(p);
      }
      int byte = (lo * 128 + (kb * 32 + hi * 8)) ^ ((lo & 7) << 4);
      *(bf16x4*)(PsW + byte) = pk;
    }
    __builtin_amdgcn_s_setprio(1);
#pragma unroll
    for (int ks2 = 0; ks2 < 2; ks2++) {
      int byte = (lo * 128 + (ks2 * 32 + hi * 8) * 2) ^ ((lo & 7) << 4);
      bf16x8 pa = *(const bf16x8*)(PsW + byte);
#pragma unroll
      for (int vc = 0; vc < 13; vc++) {
        int dv = vc * 16 + lo;
        int vbyte = (dv * 128 + (ks2 * 32 + hi * 8) * 2) ^ ((dv & 7) << 4);
        bf16x8 bv = *(const bf16x8*)((char*)Vs + vbyte);
        o_acc[vc] = __builtin_amdgcn_mfma_f32_16x16x32_bf16(pa, bv, o_acc[vc], 0, 0, 0);
      }
    }
    __builtin_amdgcn_s_setprio(0);
    __syncthreads();
  }
#pragma unroll
  for (int i = 0; i < 4; i++) {
    int row = i0 + w * 16 + hi * 4 + i;
    unsigned short* orow = Opart + (size_t)sp * SEQ * (NHEAD * DV) +
                           (size_t)row * (NHEAD * DV) + h * DV;
#pragma unroll
    for (int vc = 0; vc < 12; vc++) orow[vc * 16 + lo] = f2bf(o_acc[vc][i]);
    if (lo == 0) lbuf[((size_t)sp * NHEAD + h) * SEQ + row] = o_acc[12][i];
  }
}

// ===== MFMA pairwise attention; combined qkv buffer (stride 384); bf16 out; fused scP =====
__global__ __launch_bounds__(256) void pw_attn_mfma(const unsigned short* __restrict__ pqkv,
    const float* __restrict__ resid, unsigned short* __restrict__ out,
    float* __restrict__ scP) {
  __shared__ unsigned short Ks[64 * 128];
  __shared__ unsigned short Vs[128 * 64];
  __shared__ unsigned short Ps[4][16 * 64];
  int qb = blockIdx.x, nl = blockIdx.y, t = threadIdx.x;
  int i0 = qb * 64;
  int w = t >> 6, l = t & 63;
  int lo = l & 15, hi = l >> 4;
  size_t nrow = (size_t)nl * NP;

  bf16x8 qf[4];
  {
    const unsigned short* qp = pqkv + (nrow + i0 + w * 16 + lo) * 384 + hi * 8;
#pragma unroll
    for (int ks = 0; ks < 4; ks++) qf[ks] = *(const bf16x8*)(qp + ks * 32);
  }
  float m_s[4], l_s[4];
  f32x4 o_acc[8];
#pragma unroll
  for (int i = 0; i < 4; i++) { m_s[i] = -1e30f; l_s[i] = 0.f; }
#pragma unroll
  for (int vc = 0; vc < 8; vc++) o_acc[vc] = (f32x4){0.f, 0.f, 0.f, 0.f};
  char* PsW = (char*)&Ps[w][0];

  for (int k0 = 0; k0 < NP; k0 += 64) {
    {
      int row = t >> 2, d0 = (t & 3) * 32;
      const unsigned short* src = pqkv + (nrow + k0 + row) * 384 + DP + d0;
#pragma unroll
      for (int jj = 0; jj < 4; jj++) {
        bf16x8 a = *(const bf16x8*)(src + jj * 8);
        int byte = (row * 256 + (d0 + jj * 8) * 2) ^ ((row & 7) << 4);
        *(bf16x8*)((char*)Ks + byte) = a;
      }
    }
    {
      int key = t & 63, ds0 = (t >> 6) * 32;
      const unsigned short* src = pqkv + (nrow + k0 + key) * 384 + 256 + ds0;
#pragma unroll
      for (int e = 0; e < 4; e++) {
        bf16x8 a = *(const bf16x8*)(src + e * 8);
#pragma unroll
        for (int e2 = 0; e2 < 8; e2++) {
          int dv = ds0 + e * 8 + e2;
          *(unsigned short*)((char*)Vs + ((dv * 128 + key * 2) ^ ((dv & 7) << 4))) =
              (unsigned short)a[e2];
        }
      }
    }
    __syncthreads();
    f32x4 sacc[4];
#pragma unroll
    for (int cs = 0; cs < 4; cs++) sacc[cs] = (f32x4){0.f, 0.f, 0.f, 0.f};
    __builtin_amdgcn_s_setprio(1);
#pragma unroll
    for (int ks = 0; ks < 4; ks++) {
#pragma unroll
      for (int cs = 0; cs < 4; cs++) {
        int key = cs * 16 + lo;
        int byte = (key * 256 + (ks * 32 + hi * 8) * 2) ^ ((key & 7) << 4);
        bf16x8 bk = *(const bf16x8*)((char*)Ks + byte);
        sacc[cs] = __builtin_amdgcn_mfma_f32_16x16x32_bf16(qf[ks], bk, sacc[cs], 0, 0, 0);
      }
    }
    __builtin_amdgcn_s_setprio(0);
#pragma unroll
    for (int i = 0; i < 4; i++) {
      float mrow = fmaxf(fmaxf(sacc[0][i], sacc[1][i]), fmaxf(sacc[2][i], sacc[3][i]));
#pragma unroll
      for (int ofs = 1; ofs < 16; ofs <<= 1) mrow = fmaxf(mrow, __shfl_xor(mrow, ofs, 64));
      float mn = fmaxf(m_s[i], mrow);
      float mnl = mn * LOG2E;
      float scale = __builtin_amdgcn_exp2f(fmaf(m_s[i], LOG2E, -mnl));
      float ts = 0.f;
      int r = hi * 4 + i;
#pragma unroll
      for (int cs = 0; cs < 4; cs++) {
        float p = __builtin_amdgcn_exp2f(fmaf(sacc[cs][i], LOG2E, -mnl));
        ts += p;
        int key = cs * 16 + lo;
        int byte = (r * 128 + key * 2) ^ ((r & 7) << 4);
        *(unsigned short*)(PsW + byte) = f2bf(p);
      }
#pragma unroll
      for (int ofs = 1; ofs < 16; ofs <<= 1) ts += __shfl_xor(ts, ofs, 64);
      l_s[i] = l_s[i] * scale + ts;
      m_s[i] = mn;
#pragma unroll
      for (int vc = 0; vc < 8; vc++) o_acc[vc][i] *= scale;
    }
    __builtin_amdgcn_s_setprio(1);
#pragma unroll
    for (int ks2 = 0; ks2 < 2; ks2++) {
      int byte = (lo * 128 + (ks2 * 32 + hi * 8) * 2) ^ ((lo & 7) << 4);
      bf16x8 pa = *(const bf16x8*)(PsW + byte);
#pragma unroll
      for (int vc = 0; vc < 8; vc++) {
        int dv = vc * 16 + lo;
        int vbyte = (dv * 128 + (ks2 * 32 + hi * 8) * 2) ^ ((dv & 7) << 4);
        bf16x8 bv = *(const bf16x8*)((char*)Vs + vbyte);
        o_acc[vc] = __builtin_amdgcn_mfma_f32_16x16x32_bf16(pa, bv, o_acc[vc], 0, 0, 0);
      }
    }
    __builtin_amdgcn_s_setprio(0);
    __syncthreads();
  }
#pragma unroll
  for (int i = 0; i < 4; i++) {
    float inv = 1.0f / l_s[i];
    size_t growi = nrow + i0 + w * 16 + hi * 4 + i;
    size_t grow = growi * DP;
    float ss = 0.f;
#pragma unroll
    for (int vc = 0; vc < 8; vc++) {
      int dv = vc * 16 + lo;
      float v = o_acc[vc][i] * inv + resid[grow + dv];
      out[grow + dv] = f2bf(v);
      ss += v * v;
    }
#pragma unroll
    for (int ofs = 1; ofs < 16; ofs <<= 1) ss += __shfl_xor(ss, ofs, 64);
    if (lo == 0) scP[growi] = rsqrtf(ss * (1.0f / DP) + EPS_RMS);
  }
}

extern "C" void kernel_launch(void* const* d_in, const int* in_sizes, int n_in,
                              void* d_out, int out_size, void* d_ws, size_t ws_size,
                              hipStream_t stream) {
  const float* in_single   = (const float*)d_in[0];
  const float* in_pair     = (const float*)d_in[1];
  const float* attn_pre_w  = (const float*)d_in[2];
  const float* attn_post_w = (const float*)d_in[3];
  const float* qkv_w       = (const float*)d_in[4];
  const float* q_norm_w    = (const float*)d_in[5];
  const float* k_norm_w    = (const float*)d_in[6];
  const float* v_norm_w    = (const float*)d_in[7];
  const float* bias_rms_w  = (const float*)d_in[8];
  const float* bias_proj_w = (const float*)d_in[9];
  const float* out_w       = (const float*)d_in[10];
  const float* ff_pre_w    = (const float*)d_in[11];
  const float* ff_post_w   = (const float*)d_in[12];
  const float* ff_w1       = (const float*)d_in[13];
  const float* ff_b1       = (const float*)d_in[14];
  const float* ff_w2       = (const float*)d_in[15];
  const float* ff_b2       = (const float*)d_in[16];
  const float* pw_attn_pre = (const float*)d_in[17];
  const float* pw_qk_w     = (const float*)d_in[18];
  const float* pw_v_w      = (const float*)d_in[19];
  const float* pw_v_b      = (const float*)d_in[20];
  const float* pw_ff_pre   = (const float*)d_in[21];
  const float* pw_ff_w1    = (const float*)d_in[22];
  const float* pw_ff_b1    = (const float*)d_in[23];
  const float* pw_ff_w2    = (const float*)d_in[24];
  const float* pw_ff_b2    = (const float*)d_in[25];

  float* ws = (float*)d_ws;
  float* S    = ws;                  // 1,572,864
  float* Pc   = ws + 1572864;        // 8,388,608 (f32 pairwise trunk)
  float* Pa   = ws + 9961472;        // 8,388,608 (Opart/lbuf during attn; Pa_bf during pw)
  float* pbt  = ws + 18350080;       // 524,288
  float* pos  = ws + 18874368;       // 262,144
  float* scP  = ws + 19136512;       // 65,536
  float* scS  = ws + 19202048;       // 2,048
  float* TMP  = ws + 19204096;       // 8,650,752 (union)
  unsigned short* qkv_bf = (unsigned short*)TMP;
  unsigned short* q_r_bf = (unsigned short*)(TMP + 2752512);
  unsigned short* k_n_bf = (unsigned short*)(TMP + 3801088);
  unsigned short* v_t_bf = (unsigned short*)(TMP + 3932160);
  float* t2   = TMP + 655360;
  unsigned short* t1_bf = (unsigned short*)(TMP + 2752512);
  unsigned short* Opart = (unsigned short*)Pa;
  float* lbuf = Pa + 6500000;
  unsigned short* Pa_bf = (unsigned short*)Pa;   // 65536x128 ush (pw section only)
  float* bias384       = TMP + 6420000;
  // persistent bf16 weight arena past TMP
  unsigned short* Warena = (unsigned short*)(ws + 27854848);
  unsigned short* Wpw = Warena + (size_t)4 * 4571136;
  // full-size pairwise buffers past arena (ws total ≈ 174 MB)
  unsigned short* pqkv_full = (unsigned short*)(ws + 37111808);  // 65536 x 384 ush
  unsigned short* hh_full   = pqkv_full;                          // overlay

  float* outS = (float*)d_out;
  float* outP = outS + (size_t)SEQ * DMODEL;

  pos_kernel<<<SEQ, 64, 0, stream>>>(pos);
  rowscale_kernel<<<SEQ, 64, 0, stream>>>(in_single, scS, DMODEL);
  biasbuild_kernel<<<2, 384, 0, stream>>>(pw_v_b, bias384);

  // one-shot batched weight conversion (all 24 weights)
  {
    ConvBatch cb;
    int idx = 0, base = 0;
    auto add = [&](const float* s, unsigned short* d, int K, int N) {
      cb.src[idx] = s; cb.dst[idx] = d; cb.K[idx] = K; cb.N[idx] = N; cb.base[idx] = base;
      base += (N / 32) * (K / 32);
      idx++;
    };
    for (int l = 0; l < 4; l++) {
      unsigned short* WA = Warena + (size_t)l * 4571136;
      add(qkv_w + (size_t)l * DMODEL * QKVN, WA, DMODEL, QKVN);
      add(out_w + (size_t)l * (NHEAD * DV) * DMODEL, WA + 1032192, NHEAD * DV, DMODEL);
      add(ff_w1 + (size_t)l * DMODEL * FFI, WA + 2211840, DMODEL, FFI);
      add(ff_w2 + (size_t)l * FFI * DMODEL, WA + 3391488, FFI, DMODEL);
    }
    for (int j = 0; j < 2; j++) {
      unsigned short* WEF = Wpw + (size_t)j * 114688;
      add(pw_qk_w + (size_t)j * DP * 2 * DP, WEF, DP, 2 * DP);
      add(pw_v_w + (size_t)j * DP * DP, WEF + 256 * DP, DP, DP);
      add(pw_ff_w1 + (size_t)j * DP * DPI, WEF + 49152, DP, DPI);
      add(pw_ff_w2 + (size_t)j * DPI * DP, WEF + 81920, DPI, DP);
    }
    convT_batch<<<base, 256, 0, stream>>>(cb, idx);
  }

  for (int i = 0; i < 4; i++) {
    int j = i / 2;
    unsigned short* WA  = Warena + (size_t)i * 4571136;
    unsigned short* WO  = WA + 1032192;
    unsigned short* WF1 = WA + 2211840;
    unsigned short* WF2 = WA + 3391488;
    unsigned short* WEF = Wpw + (size_t)j * 114688;
    unsigned short* WG  = WEF + 49152;
    unsigned short* WH  = WEF + 81920;

    // P source: layer 0 reads original input; 1,2 read Pc; 3 reads final outP
    const float* Psrc = (i == 0) ? in_pair : ((i == 3) ? outP : Pc);
    const float* Ssrc = (i == 0) ? in_single : S;

    pb_kernel<<<2048, 256, 0, stream>>>(Psrc, scP, bias_rms_w + i * DP,
                                        bias_proj_w + (size_t)i * DP * 8, pbt);
    gemm_k<0, 1, 0, 1><<<21 * 32, 256, 0, stream>>>(Ssrc, WA, qkv_bf, SEQ, QKVN, DMODEL, 21,
                                                    nullptr, nullptr, 0, scS, attn_pre_w + i * DMODEL);
    qkv_prep_kernel<<<dim3(SEQ, 10), 64, 0, stream>>>(qkv_bf, q_norm_w + i * DQK,
                                                      k_norm_w + i * DQK, v_norm_w + i * DV,
                                                      pos, q_r_bf, k_n_bf, v_t_bf);
    attn_mfma<<<dim3(SEQ / 64, NHEAD, NSPLIT), 256, 0, stream>>>(q_r_bf, k_n_bf, v_t_bf, pbt,
                                                                 Opart, lbuf);
    gemm_k<2, 0, 0, 1><<<12 * 32, 256, 0, stream>>>(Opart, WO, t2, SEQ, DMODEL, NHEAD * DV, 12,
                                                    nullptr, nullptr, 0, nullptr, nullptr, lbuf);
    rmsres_kernel<<<SEQ, 64, 0, stream>>>(t2, attn_post_w + i * DMODEL, Ssrc, S, DMODEL, scS);
    gemm_k<0, 1, 0, 1><<<24 * 32, 256, 0, stream>>>(S, WF1, t1_bf, SEQ, FFI, DMODEL, 24,
                                                    ff_b1 + i * FFI, nullptr, 1, scS, ff_pre_w + i * DMODEL);
    gemm_k<1, 0, 0, 1><<<12 * 32, 256, 0, stream>>>(t1_bf, WF2, t2, SEQ, DMODEL, FFI, 12,
                                                    ff_b2 + i * DMODEL, nullptr, 0, nullptr, nullptr);
    float* Sdst = (i == 3) ? outS : S;
    rmsres_kernel<<<SEQ, 64, 0, stream>>>(t2, ff_post_w + i * DMODEL, S, Sdst, DMODEL, scS);
    // pairwise track (layers 0, 2), full-size; Pa stored bf16
    if ((i & 1) == 0) {
      float* Pdst = (i == 2) ? outP : Pc;
      gemm_k<0, 1><<<3 * 1024, 256, 0, stream>>>(Psrc, WEF, pqkv_full, NPR, 384, DP, 3,
                                                 bias384 + j * 384, nullptr, 0,
                                                 scP, pw_attn_pre + j * DP);
      pw_attn_mfma<<<dim3(4, 256), 256, 0, stream>>>(pqkv_full, Psrc, Pa_bf, scP);
      gemm_k<3, 1><<<2 * 1024, 256, 0, stream>>>(Pa_bf, WG, hh_full, NPR, DPI, DP, 2,
                                                 pw_ff_b1 + j * DPI, nullptr, 1,
                                                 scP, pw_ff_pre + j * DP);
      gemm_k<1, 0, 1><<<1 * 1024, 256, 0, stream>>>(hh_full, WH, Pdst, NPR, DP, DPI, 1,
                                                    pw_ff_b2 + j * DP, Pa_bf, 0, nullptr, nullptr);
    }
  }
}

// Round 27
// 1076.367 us; speedup vs baseline: 1.0305x; 1.0305x over previous
//
#include <hip/hip_runtime.h>
#include <hip/hip_bf16.h>

#define SEQ 2048
#define DMODEL 768
#define NHEAD 8
#define DQK 128
#define DV 192
#define QKVN 1344
#define FFI 1536
#define NP 256
#define DP 128
#define DPI 256
#define NPR 65536
#define KVB 64
#define NSPLIT 4

#define EPS_RMS 1.1920929e-07f
#define EPS_LN 1e-5f
#define LOG2E 1.4426950408889634f
#define C1_LOG2E 0.5770780163555852f   // 0.4 * log2(e)
#define C2_LOG2E -14.426950408889634f  // -10 * log2(e)

typedef __attribute__((ext_vector_type(8))) short bf16x8;
typedef __attribute__((ext_vector_type(4))) short bf16x4;
typedef __attribute__((ext_vector_type(4))) float f32x4;

__device__ inline float wave_sum(float v) {
#pragma unroll
  for (int o = 32; o > 0; o >>= 1) v += __shfl_xor(v, o, 64);
  return v;
}
__device__ inline unsigned short f2bf(float x) {
  unsigned int u = __float_as_uint(x);
  u += 0x7fffu + ((u >> 16) & 1u);
  return (unsigned short)(u >> 16);
}
__device__ inline float bf2f(unsigned short x) {
  unsigned int u = ((unsigned int)x) << 16;
  return __uint_as_float(u);
}

__global__ void pos_kernel(float* __restrict__ pos) {
  int i = blockIdx.x, l = threadIdx.x;
  float f = (l == 0) ? 0.1f * (float)i : 0.0f;
  pos[i * 128 + l] = f;
  pos[i * 128 + 64 + l] = f;
}

__global__ void rowscale_kernel(const float* __restrict__ x, float* __restrict__ sc, int cols) {
  size_t row = blockIdx.x;
  int l = threadIdx.x;
  const float* xr = x + row * cols;
  float ss = 0.f;
  for (int c = l; c < cols; c += 64) { float v = xr[c]; ss += v * v; }
  ss = wave_sum(ss);
  if (l == 0) sc[row] = rsqrtf(ss / (float)cols + EPS_RMS);
}

// y = rmsnorm(x,w) + res; also writes sc[row] = inv-rms of y
__global__ void rmsres_kernel(const float* __restrict__ x, const float* __restrict__ w,
                              const float* res, float* y, int cols, float* __restrict__ sc) {
  size_t row = blockIdx.x;
  int l = threadIdx.x;
  const float* xr = x + row * cols;
  float ss = 0.f;
  for (int c = l; c < cols; c += 64) { float v = xr[c]; ss += v * v; }
  ss = wave_sum(ss);
  float r = rsqrtf(ss / (float)cols + EPS_RMS);
  float* yr = y + row * cols;
  const float* rr = res + row * cols;
  float ss2 = 0.f;
  for (int c = l; c < cols; c += 64) {
    float v = xr[c] * r * w[c] + rr[c];
    yr[c] = v;
    ss2 += v * v;
  }
  ss2 = wave_sum(ss2);
  if (l == 0) sc[row] = rsqrtf(ss2 / (float)cols + EPS_RMS);
}

// ===== batched weight transpose+convert: all 24 weights in one launch =====
struct ConvBatch {
  const float* src[24];
  unsigned short* dst[24];
  int K[24];
  int N[24];
  int base[24];
};

__global__ __launch_bounds__(256) void convT_batch(ConvBatch cb, int nw) {
  __shared__ float ls[32][33];
  int bid = blockIdx.x;
  int w = 0;
  while (w + 1 < nw && bid >= cb.base[w + 1]) w++;
  int local = bid - cb.base[w];
  int K = cb.K[w], N = cb.N[w];
  int ntn = N >> 5;
  int n0 = (local % ntn) * 32, k0 = (local / ntn) * 32;
  const float* W = cb.src[w];
  unsigned short* Wt = cb.dst[w];
  int t = threadIdx.x;
  int c = t & 31, r4 = t >> 5;
#pragma unroll
  for (int p = 0; p < 4; p++) {
    int r = r4 + p * 8;
    ls[r][c] = W[(size_t)(k0 + r) * N + n0 + c];
  }
  __syncthreads();
#pragma unroll
  for (int p = 0; p < 4; p++) {
    int n = r4 + p * 8, k = t & 31;
    Wt[(size_t)(n0 + n) * K + k0 + k] = f2bf(ls[k][n]);
  }
}

// build pairwise combined bias: [j][384] = [0 x256 | pw_v_b[j]]
__global__ void biasbuild_kernel(const float* __restrict__ pw_v_b, float* __restrict__ b384) {
  int j = blockIdx.x, t = threadIdx.x;
  b384[j * 384 + t] = (t < 256) ? 0.f : pw_v_b[j * DP + t - 256];
}

// ===== combine NSPLIT Opart splits: Oc = (sum_sp Opart) / (sum_sp l) =====
__global__ void ocomb_kernel(const unsigned short* __restrict__ Opart,
                             const float* __restrict__ lbuf,
                             unsigned short* __restrict__ Oc) {
  int row = blockIdx.x, c8 = threadIdx.x;   // c8 in [0,192): one bf16x8 chunk
  int h = c8 / 24;                          // (c8*8)/DV
  float lsum = 0.f;
#pragma unroll
  for (int sp = 0; sp < NSPLIT; sp++)
    lsum += lbuf[((size_t)sp * NHEAD + h) * SEQ + row];
  float linv = 1.0f / lsum;
  size_t base = (size_t)row * (NHEAD * DV) + c8 * 8;
  bf16x8 a[NSPLIT];
#pragma unroll
  for (int sp = 0; sp < NSPLIT; sp++)
    a[sp] = *(const bf16x8*)(Opart + (size_t)sp * SEQ * (NHEAD * DV) + base);
  bf16x8 o;
#pragma unroll
  for (int e = 0; e < 8; e++) {
    float s = 0.f;
#pragma unroll
    for (int sp = 0; sp < NSPLIT; sp++) s += bf2f((unsigned short)a[sp][e]);
    o[e] = (short)f2bf(s * linv);
  }
  *(bf16x8*)(Oc + base) = o;
}

// ===== templated MFMA GEMM: 64x128 or 64x64 tile, reg-prefetch, XCD swizzle =====
// AMODE: 0 = f32 A (+opt rmsnorm scale), 1 = bf16 A, 2 = combine(2 Opart splits, lbuf),
//        3 = bf16 A (+rmsnorm scale). CBF: C bf16. RBF: resid is bf16. BN64: 64-wide N tile.
template<int AMODE, int CBF, int RBF = 0, int BN64 = 0>
__global__ __launch_bounds__(256) void gemm_k(const void* __restrict__ Av,
    const unsigned short* __restrict__ Bt, void* __restrict__ Cv,
    int M, int N, int K, int nbx,
    const float* __restrict__ bias, const void* __restrict__ resid, int act,
    const float* __restrict__ ascale, const float* __restrict__ aw,
    const float* __restrict__ lb = nullptr) {
  constexpr int BN = BN64 ? 64 : 128;
  constexpr int NC = BN64 ? 2 : 4;
  __shared__ unsigned short As[64 * 32];
  __shared__ unsigned short Bs[BN * 32];
  int t = threadIdx.x;
  int nwg = gridDim.x, bid = blockIdx.x;
  int qq = nwg >> 3, rr = nwg & 7, xc = bid & 7, ii = bid >> 3;
  int swz = (xc < rr ? xc * (qq + 1) : rr * (qq + 1) + (xc - rr) * qq) + ii;
  int bm = (swz / nbx) * 64, bn = (swz % nbx) * BN;
  int w = t >> 6, l = t & 63;
  int wr = (w >> 1) * 32, wc = (w & 1) * (BN / 2);
  int lo = l & 15, hi = l >> 4;
  f32x4 acc[2][NC];
#pragma unroll
  for (int q = 0; q < 2; q++)
#pragma unroll
    for (int cb = 0; cb < NC; cb++) acc[q][cb] = (f32x4){0.f, 0.f, 0.f, 0.f};

  int arow = t >> 2, acs = (t & 3) * 8;
  int brow = BN64 ? (t >> 2) : (t >> 1);
  int bks  = BN64 ? ((t & 3) * 8) : ((t & 1) * 16);
  int bok = (bn + brow < N);
  const unsigned short* bsrc = Bt + (size_t)(bok ? bn + brow : 0) * K + bks;

  float4 pa0, pa1;
  bf16x8 pab, pc1, pb0, pb1;
  float linv = 1.f;
  const bf16x8 zb = {0, 0, 0, 0, 0, 0, 0, 0};

  {
    if (AMODE == 2) {
      const unsigned short* Op = (const unsigned short*)Av;
      size_t base = (size_t)(bm + arow) * K + acs;
      pab = *(const bf16x8*)(Op + base);
      pc1 = *(const bf16x8*)(Op + (size_t)SEQ * K + base);
      int h = acs / DV;
      linv = 1.0f / (lb[(size_t)h * SEQ + bm + arow] +
                     lb[(size_t)(NHEAD + h) * SEQ + bm + arow]);
    } else if (AMODE == 1 || AMODE == 3) {
      pab = *(const bf16x8*)((const unsigned short*)Av + (size_t)(bm + arow) * K + acs);
    } else {
      const float* A = (const float*)Av;
      pa0 = *(const float4*)(A + (size_t)(bm + arow) * K + acs);
      pa1 = *(const float4*)(A + (size_t)(bm + arow) * K + acs + 4);
    }
    pb0 = bok ? *(const bf16x8*)(bsrc) : zb;
    if (!BN64) pb1 = bok ? *(const bf16x8*)(bsrc + 8) : zb;
  }

  for (int k0 = 0; k0 < K; k0 += 32) {
    if (k0) __syncthreads();
    {
      int byte = (arow * 64 + acs * 2) ^ ((arow & 7) << 4);
      if (AMODE == 2) {
        bf16x8 cmb;
#pragma unroll
        for (int e = 0; e < 8; e++)
          cmb[e] = (short)f2bf((bf2f((unsigned short)pab[e]) +
                                bf2f((unsigned short)pc1[e])) * linv);
        *(bf16x8*)((char*)As + byte) = cmb;
      } else if (AMODE == 3) {
        float s = ascale[bm + arow];
        bf16x8 sc8;
#pragma unroll
        for (int e = 0; e < 8; e++)
          sc8[e] = (short)f2bf(bf2f((unsigned short)pab[e]) * s * aw[k0 + acs + e]);
        *(bf16x8*)((char*)As + byte) = sc8;
      } else if (AMODE == 1) {
        *(bf16x8*)((char*)As + byte) = pab;
      } else {
        float4 v0 = pa0, v1 = pa1;
        if (ascale) {
          float s = ascale[bm + arow];
          v0.x *= s * aw[k0 + acs + 0]; v0.y *= s * aw[k0 + acs + 1];
          v0.z *= s * aw[k0 + acs + 2]; v0.w *= s * aw[k0 + acs + 3];
          v1.x *= s * aw[k0 + acs + 4]; v1.y *= s * aw[k0 + acs + 5];
          v1.z *= s * aw[k0 + acs + 6]; v1.w *= s * aw[k0 + acs + 7];
        }
        uint4 pk;
        pk.x = (unsigned int)f2bf(v0.x) | ((unsigned int)f2bf(v0.y) << 16);
        pk.y = (unsigned int)f2bf(v0.z) | ((unsigned int)f2bf(v0.w) << 16);
        pk.z = (unsigned int)f2bf(v1.x) | ((unsigned int)f2bf(v1.y) << 16);
        pk.w = (unsigned int)f2bf(v1.z) | ((unsigned int)f2bf(v1.w) << 16);
        *(uint4*)((char*)As + byte) = pk;
      }
      int b0 = (brow * 64 + bks * 2) ^ ((brow & 7) << 4);
      *(bf16x8*)((char*)Bs + b0) = pb0;
      if (!BN64) {
        int b1 = (brow * 64 + bks * 2 + 16) ^ ((brow & 7) << 4);
        *(bf16x8*)((char*)Bs + b1) = pb1;
      }
    }
    __syncthreads();
    if (k0 + 32 < K) {
      int kn = k0 + 32;
      if (AMODE == 2) {
        const unsigned short* Op = (const unsigned short*)Av;
        size_t base = (size_t)(bm + arow) * K + kn + acs;
        pab = *(const bf16x8*)(Op + base);
        pc1 = *(const bf16x8*)(Op + (size_t)SEQ * K + base);
        int h = (kn + acs) / DV;
        linv = 1.0f / (lb[(size_t)h * SEQ + bm + arow] +
                       lb[(size_t)(NHEAD + h) * SEQ + bm + arow]);
      } else if (AMODE == 1 || AMODE == 3) {
        pab = *(const bf16x8*)((const unsigned short*)Av + (size_t)(bm + arow) * K + kn + acs);
      } else {
        const float* A = (const float*)Av;
        pa0 = *(const float4*)(A + (size_t)(bm + arow) * K + kn + acs);
        pa1 = *(const float4*)(A + (size_t)(bm + arow) * K + kn + acs + 4);
      }
      pb0 = bok ? *(const bf16x8*)(bsrc + kn) : zb;
      if (!BN64) pb1 = bok ? *(const bf16x8*)(bsrc + kn + 8) : zb;
    }
    bf16x8 af[2], bfr[NC];
#pragma unroll
    for (int q = 0; q < 2; q++) {
      int r = wr + q * 16 + lo;
      af[q] = *(const bf16x8*)((char*)As + ((r * 64 + hi * 16) ^ ((r & 7) << 4)));
    }
#pragma unroll
    for (int cb = 0; cb < NC; cb++) {
      int n = wc + cb * 16 + lo;
      bfr[cb] = *(const bf16x8*)((char*)Bs + ((n * 64 + hi * 16) ^ ((n & 7) << 4)));
    }
#pragma unroll
    for (int q = 0; q < 2; q++)
#pragma unroll
      for (int cb = 0; cb < NC; cb++)
        acc[q][cb] = __builtin_amdgcn_mfma_f32_16x16x32_bf16(af[q], bfr[cb], acc[q][cb], 0, 0, 0);
  }
#pragma unroll
  for (int q = 0; q < 2; q++) {
#pragma unroll
    for (int cb = 0; cb < NC; cb++) {
      int gn = bn + wc + cb * 16 + lo;
      if (gn >= N) continue;
#pragma unroll
      for (int i = 0; i < 4; i++) {
        int gm = bm + wr + q * 16 + hi * 4 + i;
        float v = acc[q][cb][i];
        if (bias) v += bias[gn];
        if (act) v = fmaxf(v, 0.f);
        if (resid) {
          size_t ridx = (size_t)gm * N + gn;
          v += RBF ? bf2f(((const unsigned short*)resid)[ridx])
                   : ((const float*)resid)[ridx];
        }
        if (CBF) {
          ((unsigned short*)Cv)[(size_t)gm * N + gn] = f2bf(v);
        } else {
          ((float*)Cv)[(size_t)gm * N + gn] = v;
        }
      }
    }
  }
}

// merged q/k/v prep (bf16 input) -> bf16 outputs. grid (SEQ, 10)
__global__ void qkv_prep_kernel(const unsigned short* __restrict__ qkv,
                                const float* __restrict__ qw,
                                const float* __restrict__ kw, const float* __restrict__ vw,
                                const float* __restrict__ pos,
                                unsigned short* __restrict__ q_r, unsigned short* __restrict__ k_n,
                                unsigned short* __restrict__ v_t) {
  int i = blockIdx.x;
  int y = blockIdx.y;
  int l = threadIdx.x;
  if (y == 9) {
    const unsigned short* row = qkv + (size_t)i * QKVN + NHEAD * DQK + DQK;
    float x0 = bf2f(row[l]), x1 = bf2f(row[l + 64]), x2 = bf2f(row[l + 128]);
    float mu = wave_sum(x0 + x1 + x2) * (1.0f / 192.0f);
    float d0 = x0 - mu, d1 = x1 - mu, d2 = x2 - mu;
    float var = wave_sum(d0 * d0 + d1 * d1 + d2 * d2) * (1.0f / 192.0f);
    float rs = rsqrtf(var + EPS_LN);
    v_t[(size_t)l * SEQ + i] = f2bf(d0 * rs * vw[l]);
    v_t[(size_t)(l + 64) * SEQ + i] = f2bf(d1 * rs * vw[l + 64]);
    v_t[(size_t)(l + 128) * SEQ + i] = f2bf(d2 * rs * vw[l + 128]);
    return;
  }
  int off = (y < 8) ? y * DQK : NHEAD * DQK;
  const unsigned short* row = qkv + (size_t)i * QKVN + off;
  float a = bf2f(row[l]), b = bf2f(row[l + 64]);
  float mu = wave_sum(a + b) * (1.0f / 128.0f);
  float da = a - mu, db = b - mu;
  float var = wave_sum(da * da + db * db) * (1.0f / 128.0f);
  float rs = rsqrtf(var + EPS_LN);
  const float* w = (y < 8) ? qw : kw;
  float na = da * rs * w[l], nb = db * rs * w[l + 64];
  if (y < 8) { na *= 0.125f; nb *= 0.125f; }
  float p0 = pos[i * 128 + l], p1 = pos[i * 128 + 64 + l];
  float ra = na * cosf(p0) - nb * sinf(p0);
  float rb = nb * cosf(p1) + na * sinf(p1);
  if (y < 8) {
    unsigned short* o = q_r + ((size_t)y * SEQ + i) * DQK;
    o[l] = f2bf(ra); o[l + 64] = f2bf(rb);
  } else {
    unsigned short* o = k_n + (size_t)i * DQK;
    o[l] = f2bf(ra); o[l + 64] = f2bf(rb);
  }
}

// fused bias projection + scP writer
__global__ __launch_bounds__(256) void pb_kernel(const float* __restrict__ P,
    float* __restrict__ scP, const float* __restrict__ rmsw,
    const float* __restrict__ proj, float* __restrict__ pbt) {
  __shared__ float gs[32][130];
  __shared__ float projs[1024];
  int b = blockIdx.x, t = threadIdx.x;
  int row0 = b * 32;
  int wv = t >> 6, ln = t & 63;
  for (int f = t; f < 1024; f += 256) projs[f] = proj[f];
#pragma unroll
  for (int rr = 0; rr < 8; rr++) {
    int r = wv * 8 + rr;
    const float* src = P + (size_t)(row0 + r) * DP;
    float2 x = *(const float2*)(src + ln * 2);
    float ss = wave_sum(x.x * x.x + x.y * x.y);
    float rs = rsqrtf(ss * (1.0f / DP) + EPS_RMS);
    float g0 = x.x * rs * rmsw[ln * 2];
    float g1 = x.y * rs * rmsw[ln * 2 + 1];
    gs[r][ln * 2] = 0.5f * g0 * (1.0f + erff(g0 * 0.70710678118654752f));
    gs[r][ln * 2 + 1] = 0.5f * g1 * (1.0f + erff(g1 * 0.70710678118654752f));
    if (ln == 0) scP[row0 + r] = rs;
  }
  __syncthreads();
  int hh = t >> 5, r = t & 31;
  float acc = 0.f;
#pragma unroll 4
  for (int d = 0; d < 128; d++) acc += gs[r][d] * projs[d * 8 + hh];
  pbt[(size_t)hh * NPR + row0 + r] = acc;
}

// ===== split-K MFMA flash attention: fixed-max softmax (raw exp2/rcp), swapped QK,
//       l via MFMA ones-column. grid (SEQ/64, NHEAD, NSPLIT). =====
__global__ __launch_bounds__(256) void attn_mfma(const unsigned short* __restrict__ q_r,
    const unsigned short* __restrict__ k_n, const unsigned short* __restrict__ v_t,
    const float* __restrict__ pbt, unsigned short* __restrict__ Opart,
    float* __restrict__ lbuf) {
  __shared__ unsigned short Ks[64 * 128];
  __shared__ unsigned short Vs[208 * 64];
  __shared__ unsigned short Ps[4][16 * 64];
  __shared__ float pb_lds[64];
  int ib = blockIdx.x, h = blockIdx.y, sp = blockIdx.z, t = threadIdx.x;
  int i0 = ib * 64;
  int w = t >> 6, l = t & 63;
  int lo = l & 15, hi = l >> 4;
  int kbeg = sp * (SEQ / NSPLIT), kend = kbeg + SEQ / NSPLIT;

  bf16x8 qf[4];
  {
    const unsigned short* qp = q_r + ((size_t)h * SEQ + i0 + w * 16 + lo) * DQK + hi * 8;
#pragma unroll
    for (int ks = 0; ks < 4; ks++) qf[ks] = *(const bf16x8*)(qp + ks * 32);
  }
  f32x4 o_acc[13];
#pragma unroll
  for (int vc = 0; vc < 13; vc++) o_acc[vc] = (f32x4){0.f, 0.f, 0.f, 0.f};

#pragma unroll
  for (int r4 = 0; r4 < 4; r4++) {
    int idx = t + 256 * r4;
    int row = 192 + (idx >> 6), key = idx & 63;
    int byte = (row * 128 + key * 2) ^ ((row & 7) << 4);
    *(unsigned short*)((char*)Vs + byte) = (row == 192) ? 0x3F80 : 0;
  }

  char* PsW = (char*)&Ps[w][0];
  int rg8 = (((w * 16 + lo) >> 3) << 3) + (hi >> 1);

  for (int k0 = kbeg; k0 < kend; k0 += KVB) {
    {
      int row = t >> 2, d0 = (t & 3) * 32;
      const unsigned short* src = k_n + (size_t)(k0 + row) * DQK + d0;
#pragma unroll
      for (int jj = 0; jj < 4; jj++) {
        bf16x8 a = *(const bf16x8*)(src + jj * 8);
        int byte = (row * 256 + (d0 + jj * 8) * 2) ^ ((row & 7) << 4);
        *(bf16x8*)((char*)Ks + byte) = a;
      }
    }
#pragma unroll
    for (int rep = 0; rep < 6; rep++) {
      int c = t + 256 * rep;
      int row = c >> 3, seg = c & 7;
      bf16x8 a = *(const bf16x8*)(v_t + (size_t)row * SEQ + k0 + seg * 8);
      int byte = (row * 128 + seg * 16) ^ ((row & 7) << 4);
      *(bf16x8*)((char*)Vs + byte) = a;
    }
    if (t < 64) {
      int rg = t >> 3, kg = t & 7;
      pb_lds[t] = C1_LOG2E * pbt[(size_t)h * NPR + ((i0 >> 3) + rg) * 256 + (k0 >> 3) + kg];
    }
    __syncthreads();
    f32x4 sacc[4];
#pragma unroll
    for (int kb = 0; kb < 4; kb++) sacc[kb] = (f32x4){0.f, 0.f, 0.f, 0.f};
#pragma unroll
    for (int ks = 0; ks < 4; ks++) {
#pragma unroll
      for (int kb = 0; kb < 4; kb++) {
        int key = kb * 16 + lo;
        int byte = (key * 256 + (ks * 32 + hi * 8) * 2) ^ ((key & 7) << 4);
        bf16x8 kf = *(const bf16x8*)((char*)Ks + byte);
        sacc[kb] = __builtin_amdgcn_mfma_f32_16x16x32_bf16(kf, qf[ks], sacc[kb], 0, 0, 0);
      }
    }
#pragma unroll
    for (int kb = 0; kb < 4; kb++) {
      float pb = pb_lds[rg8 + kb * 2];
      bf16x4 pk;
#pragma unroll
      for (int i = 0; i < 4; i++) {
        float x2 = fmaf(C1_LOG2E, sacc[kb][i], pb);
        float e = __builtin_amdgcn_exp2f(x2);
        float p = __builtin_amdgcn_exp2f(C2_LOG2E * __builtin_amdgcn_rcpf(e + 1.f));
        pk[i] = (short)f2bf(p);
      }
      int byte = (lo * 128 + (kb * 32 + hi * 8)) ^ ((lo & 7) << 4);
      *(bf16x4*)(PsW + byte) = pk;
    }
#pragma unroll
    for (int ks2 = 0; ks2 < 2; ks2++) {
      int byte = (lo * 128 + (ks2 * 32 + hi * 8) * 2) ^ ((lo & 7) << 4);
      bf16x8 pa = *(const bf16x8*)(PsW + byte);
#pragma unroll
      for (int vc = 0; vc < 13; vc++) {
        int dv = vc * 16 + lo;
        int vbyte = (dv * 128 + (ks2 * 32 + hi * 8) * 2) ^ ((dv & 7) << 4);
        bf16x8 bv = *(const bf16x8*)((char*)Vs + vbyte);
        o_acc[vc] = __builtin_amdgcn_mfma_f32_16x16x32_bf16(pa, bv, o_acc[vc], 0, 0, 0);
      }
    }
    __syncthreads();
  }
#pragma unroll
  for (int i = 0; i < 4; i++) {
    int row = i0 + w * 16 + hi * 4 + i;
    unsigned short* orow = Opart + (size_t)sp * SEQ * (NHEAD * DV) +
                           (size_t)row * (NHEAD * DV) + h * DV;
#pragma unroll
    for (int vc = 0; vc < 12; vc++) orow[vc * 16 + lo] = f2bf(o_acc[vc][i]);
    if (lo == 0) lbuf[((size_t)sp * NHEAD + h) * SEQ + row] = o_acc[12][i];
  }
}

// ===== MFMA pairwise attention; combined qkv buffer (stride 384); bf16 out; fused scP =====
__global__ __launch_bounds__(256) void pw_attn_mfma(const unsigned short* __restrict__ pqkv,
    const float* __restrict__ resid, unsigned short* __restrict__ out,
    float* __restrict__ scP) {
  __shared__ unsigned short Ks[64 * 128];
  __shared__ unsigned short Vs[128 * 64];
  __shared__ unsigned short Ps[4][16 * 64];
  int qb = blockIdx.x, nl = blockIdx.y, t = threadIdx.x;
  int i0 = qb * 64;
  int w = t >> 6, l = t & 63;
  int lo = l & 15, hi = l >> 4;
  size_t nrow = (size_t)nl * NP;

  bf16x8 qf[4];
  {
    const unsigned short* qp = pqkv + (nrow + i0 + w * 16 + lo) * 384 + hi * 8;
#pragma unroll
    for (int ks = 0; ks < 4; ks++) qf[ks] = *(const bf16x8*)(qp + ks * 32);
  }
  float m_s[4], l_s[4];
  f32x4 o_acc[8];
#pragma unroll
  for (int i = 0; i < 4; i++) { m_s[i] = -1e30f; l_s[i] = 0.f; }
#pragma unroll
  for (int vc = 0; vc < 8; vc++) o_acc[vc] = (f32x4){0.f, 0.f, 0.f, 0.f};
  char* PsW = (char*)&Ps[w][0];

  for (int k0 = 0; k0 < NP; k0 += 64) {
    {
      int row = t >> 2, d0 = (t & 3) * 32;
      const unsigned short* src = pqkv + (nrow + k0 + row) * 384 + DP + d0;
#pragma unroll
      for (int jj = 0; jj < 4; jj++) {
        bf16x8 a = *(const bf16x8*)(src + jj * 8);
        int byte = (row * 256 + (d0 + jj * 8) * 2) ^ ((row & 7) << 4);
        *(bf16x8*)((char*)Ks + byte) = a;
      }
    }
    {
      int key = t & 63, ds0 = (t >> 6) * 32;
      const unsigned short* src = pqkv + (nrow + k0 + key) * 384 + 256 + ds0;
#pragma unroll
      for (int e = 0; e < 4; e++) {
        bf16x8 a = *(const bf16x8*)(src + e * 8);
#pragma unroll
        for (int e2 = 0; e2 < 8; e2++) {
          int dv = ds0 + e * 8 + e2;
          *(unsigned short*)((char*)Vs + ((dv * 128 + key * 2) ^ ((dv & 7) << 4))) =
              (unsigned short)a[e2];
        }
      }
    }
    __syncthreads();
    f32x4 sacc[4];
#pragma unroll
    for (int cs = 0; cs < 4; cs++) sacc[cs] = (f32x4){0.f, 0.f, 0.f, 0.f};
#pragma unroll
    for (int ks = 0; ks < 4; ks++) {
#pragma unroll
      for (int cs = 0; cs < 4; cs++) {
        int key = cs * 16 + lo;
        int byte = (key * 256 + (ks * 32 + hi * 8) * 2) ^ ((key & 7) << 4);
        bf16x8 bk = *(const bf16x8*)((char*)Ks + byte);
        sacc[cs] = __builtin_amdgcn_mfma_f32_16x16x32_bf16(qf[ks], bk, sacc[cs], 0, 0, 0);
      }
    }
#pragma unroll
    for (int i = 0; i < 4; i++) {
      float mrow = fmaxf(fmaxf(sacc[0][i], sacc[1][i]), fmaxf(sacc[2][i], sacc[3][i]));
#pragma unroll
      for (int ofs = 1; ofs < 16; ofs <<= 1) mrow = fmaxf(mrow, __shfl_xor(mrow, ofs, 64));
      float mn = fmaxf(m_s[i], mrow);
      float mnl = mn * LOG2E;
      float scale = __builtin_amdgcn_exp2f(fmaf(m_s[i], LOG2E, -mnl));
      float ts = 0.f;
      int r = hi * 4 + i;
#pragma unroll
      for (int cs = 0; cs < 4; cs++) {
        float p = __builtin_amdgcn_exp2f(fmaf(sacc[cs][i], LOG2E, -mnl));
        ts += p;
        int key = cs * 16 + lo;
        int byte = (r * 128 + key * 2) ^ ((r & 7) << 4);
        *(unsigned short*)(PsW + byte) = f2bf(p);
      }
#pragma unroll
      for (int ofs = 1; ofs < 16; ofs <<= 1) ts += __shfl_xor(ts, ofs, 64);
      l_s[i] = l_s[i] * scale + ts;
      m_s[i] = mn;
#pragma unroll
      for (int vc = 0; vc < 8; vc++) o_acc[vc][i] *= scale;
    }
#pragma unroll
    for (int ks2 = 0; ks2 < 2; ks2++) {
      int byte = (lo * 128 + (ks2 * 32 + hi * 8) * 2) ^ ((lo & 7) << 4);
      bf16x8 pa = *(const bf16x8*)(PsW + byte);
#pragma unroll
      for (int vc = 0; vc < 8; vc++) {
        int dv = vc * 16 + lo;
        int vbyte = (dv * 128 + (ks2 * 32 + hi * 8) * 2) ^ ((dv & 7) << 4);
        bf16x8 bv = *(const bf16x8*)((char*)Vs + vbyte);
        o_acc[vc] = __builtin_amdgcn_mfma_f32_16x16x32_bf16(pa, bv, o_acc[vc], 0, 0, 0);
      }
    }
    __syncthreads();
  }
#pragma unroll
  for (int i = 0; i < 4; i++) {
    float inv = 1.0f / l_s[i];
    size_t growi = nrow + i0 + w * 16 + hi * 4 + i;
    size_t grow = growi * DP;
    float ss = 0.f;
#pragma unroll
    for (int vc = 0; vc < 8; vc++) {
      int dv = vc * 16 + lo;
      float v = o_acc[vc][i] * inv + resid[grow + dv];
      out[grow + dv] = f2bf(v);
      ss += v * v;
    }
#pragma unroll
    for (int ofs = 1; ofs < 16; ofs <<= 1) ss += __shfl_xor(ss, ofs, 64);
    if (lo == 0) scP[growi] = rsqrtf(ss * (1.0f / DP) + EPS_RMS);
  }
}

extern "C" void kernel_launch(void* const* d_in, const int* in_sizes, int n_in,
                              void* d_out, int out_size, void* d_ws, size_t ws_size,
                              hipStream_t stream) {
  const float* in_single   = (const float*)d_in[0];
  const float* in_pair     = (const float*)d_in[1];
  const float* attn_pre_w  = (const float*)d_in[2];
  const float* attn_post_w = (const float*)d_in[3];
  const float* qkv_w       = (const float*)d_in[4];
  const float* q_norm_w    = (const float*)d_in[5];
  const float* k_norm_w    = (const float*)d_in[6];
  const float* v_norm_w    = (const float*)d_in[7];
  const float* bias_rms_w  = (const float*)d_in[8];
  const float* bias_proj_w = (const float*)d_in[9];
  const float* out_w       = (const float*)d_in[10];
  const float* ff_pre_w    = (const float*)d_in[11];
  const float* ff_post_w   = (const float*)d_in[12];
  const float* ff_w1       = (const float*)d_in[13];
  const float* ff_b1       = (const float*)d_in[14];
  const float* ff_w2       = (const float*)d_in[15];
  const float* ff_b2       = (const float*)d_in[16];
  const float* pw_attn_pre = (const float*)d_in[17];
  const float* pw_qk_w     = (const float*)d_in[18];
  const float* pw_v_w      = (const float*)d_in[19];
  const float* pw_v_b      = (const float*)d_in[20];
  const float* pw_ff_pre   = (const float*)d_in[21];
  const float* pw_ff_w1    = (const float*)d_in[22];
  const float* pw_ff_b1    = (const float*)d_in[23];
  const float* pw_ff_w2    = (const float*)d_in[24];
  const float* pw_ff_b2    = (const float*)d_in[25];

  float* ws = (float*)d_ws;
  float* S    = ws;                  // 1,572,864
  float* Pc   = ws + 1572864;        // 8,388,608 (f32 pairwise trunk)
  float* Pa   = ws + 9961472;        // 8,388,608 (Opart[4]/lbuf during attn; Pa_bf during pw)
  float* pbt  = ws + 18350080;       // 524,288
  float* pos  = ws + 18874368;       // 262,144
  float* scP  = ws + 19136512;       // 65,536
  float* scS  = ws + 19202048;       // 2,048
  float* TMP  = ws + 19204096;       // 8,650,752 (union)
  unsigned short* qkv_bf = (unsigned short*)TMP;
  unsigned short* q_r_bf = (unsigned short*)(TMP + 2752512);
  unsigned short* k_n_bf = (unsigned short*)(TMP + 3801088);
  unsigned short* v_t_bf = (unsigned short*)(TMP + 3932160);
  float* t2   = TMP + 655360;
  unsigned short* t1_bf = (unsigned short*)(TMP + 2752512);
  unsigned short* Opart = (unsigned short*)Pa;       // 4 x SEQ x 1536 ush = 6,291,456 floats
  float* lbuf = Pa + 6500000;                        // 4 x 8 x 2048 = 65,536 floats
  unsigned short* Ocomb = (unsigned short*)(TMP + 3932160);  // SEQ x 1536 ush (v_t dead)
  unsigned short* Pa_bf = (unsigned short*)Pa;       // 65536x128 ush (pw section only)
  float* bias384       = TMP + 6420000;
  // persistent bf16 weight arena past TMP
  unsigned short* Warena = (unsigned short*)(ws + 27854848);
  unsigned short* Wpw = Warena + (size_t)4 * 4571136;
  // full-size pairwise buffers past arena
  unsigned short* pqkv_full = (unsigned short*)(ws + 37111808);  // 65536 x 384 ush
  unsigned short* hh_full   = pqkv_full;                          // overlay

  float* outS = (float*)d_out;
  float* outP = outS + (size_t)SEQ * DMODEL;

  pos_kernel<<<SEQ, 64, 0, stream>>>(pos);
  rowscale_kernel<<<SEQ, 64, 0, stream>>>(in_single, scS, DMODEL);
  biasbuild_kernel<<<2, 384, 0, stream>>>(pw_v_b, bias384);

  // one-shot batched weight conversion (all 24 weights)
  {
    ConvBatch cb;
    int idx = 0, base = 0;
    auto add = [&](const float* s, unsigned short* d, int K, int N) {
      cb.src[idx] = s; cb.dst[idx] = d; cb.K[idx] = K; cb.N[idx] = N; cb.base[idx] = base;
      base += (N / 32) * (K / 32);
      idx++;
    };
    for (int l = 0; l < 4; l++) {
      unsigned short* WA = Warena + (size_t)l * 4571136;
      add(qkv_w + (size_t)l * DMODEL * QKVN, WA, DMODEL, QKVN);
      add(out_w + (size_t)l * (NHEAD * DV) * DMODEL, WA + 1032192, NHEAD * DV, DMODEL);
      add(ff_w1 + (size_t)l * DMODEL * FFI, WA + 2211840, DMODEL, FFI);
      add(ff_w2 + (size_t)l * FFI * DMODEL, WA + 3391488, FFI, DMODEL);
    }
    for (int j = 0; j < 2; j++) {
      unsigned short* WEF = Wpw + (size_t)j * 114688;
      add(pw_qk_w + (size_t)j * DP * 2 * DP, WEF, DP, 2 * DP);
      add(pw_v_w + (size_t)j * DP * DP, WEF + 256 * DP, DP, DP);
      add(pw_ff_w1 + (size_t)j * DP * DPI, WEF + 49152, DP, DPI);
      add(pw_ff_w2 + (size_t)j * DPI * DP, WEF + 81920, DPI, DP);
    }
    convT_batch<<<base, 256, 0, stream>>>(cb, idx);
  }

  for (int i = 0; i < 4; i++) {
    int j = i / 2;
    unsigned short* WA  = Warena + (size_t)i * 4571136;
    unsigned short* WO  = WA + 1032192;
    unsigned short* WF1 = WA + 2211840;
    unsigned short* WF2 = WA + 3391488;
    unsigned short* WEF = Wpw + (size_t)j * 114688;
    unsigned short* WG  = WEF + 49152;
    unsigned short* WH  = WEF + 81920;

    // P source: layer 0 reads original input; 1,2 read Pc; 3 reads final outP
    const float* Psrc = (i == 0) ? in_pair : ((i == 3) ? outP : Pc);
    const float* Ssrc = (i == 0) ? in_single : S;

    pb_kernel<<<2048, 256, 0, stream>>>(Psrc, scP, bias_rms_w + i * DP,
                                        bias_proj_w + (size_t)i * DP * 8, pbt);
    gemm_k<0, 1, 0, 1><<<21 * 32, 256, 0, stream>>>(Ssrc, WA, qkv_bf, SEQ, QKVN, DMODEL, 21,
                                                    nullptr, nullptr, 0, scS, attn_pre_w + i * DMODEL);
    qkv_prep_kernel<<<dim3(SEQ, 10), 64, 0, stream>>>(qkv_bf, q_norm_w + i * DQK,
                                                      k_norm_w + i * DQK, v_norm_w + i * DV,
                                                      pos, q_r_bf, k_n_bf, v_t_bf);
    attn_mfma<<<dim3(SEQ / 64, NHEAD, NSPLIT), 256, 0, stream>>>(q_r_bf, k_n_bf, v_t_bf, pbt,
                                                                 Opart, lbuf);
    ocomb_kernel<<<SEQ, 192, 0, stream>>>(Opart, lbuf, Ocomb);
    gemm_k<1, 0, 0, 1><<<12 * 32, 256, 0, stream>>>(Ocomb, WO, t2, SEQ, DMODEL, NHEAD * DV, 12,
                                                    nullptr, nullptr, 0, nullptr, nullptr);
    rmsres_kernel<<<SEQ, 64, 0, stream>>>(t2, attn_post_w + i * DMODEL, Ssrc, S, DMODEL, scS);
    gemm_k<0, 1, 0, 1><<<24 * 32, 256, 0, stream>>>(S, WF1, t1_bf, SEQ, FFI, DMODEL, 24,
                                                    ff_b1 + i * FFI, nullptr, 1, scS, ff_pre_w + i * DMODEL);
    gemm_k<1, 0, 0, 1><<<12 * 32, 256, 0, stream>>>(t1_bf, WF2, t2, SEQ, DMODEL, FFI, 12,
                                                    ff_b2 + i * DMODEL, nullptr, 0, nullptr, nullptr);
    float* Sdst = (i == 3) ? outS : S;
    rmsres_kernel<<<SEQ, 64, 0, stream>>>(t2, ff_post_w + i * DMODEL, S, Sdst, DMODEL, scS);
    // pairwise track (layers 0, 2), full-size; Pa stored bf16
    if ((i & 1) == 0) {
      float* Pdst = (i == 2) ? outP : Pc;
      gemm_k<0, 1><<<3 * 1024, 256, 0, stream>>>(Psrc, WEF, pqkv_full, NPR, 384, DP, 3,
                                                 bias384 + j * 384, nullptr, 0,
                                                 scP, pw_attn_pre + j * DP);
      pw_attn_mfma<<<dim3(4, 256), 256, 0, stream>>>(pqkv_full, Psrc, Pa_bf, scP);
      gemm_k<3, 1><<<2 * 1024, 256, 0, stream>>>(Pa_bf, WG, hh_full, NPR, DPI, DP, 2,
                                                 pw_ff_b1 + j * DPI, nullptr, 1,
                                                 scP, pw_ff_pre + j * DP);
      gemm_k<1, 0, 1><<<1 * 1024, 256, 0, stream>>>(hh_full, WH, Pdst, NPR, DP, DPI, 1,
                                                    pw_ff_b2 + j * DP, Pa_bf, 0, nullptr, nullptr);
    }
  }
}